// Round 2
// baseline (1386.930 us; speedup 1.0000x reference)
//
#include <hip/hip_runtime.h>

typedef __attribute__((ext_vector_type(8))) __bf16 bf16x8;
typedef __attribute__((ext_vector_type(4))) float f4;

#define MFMA(a, b, c) __builtin_amdgcn_mfma_f32_16x16x32_bf16((a), (b), (c), 0, 0, 0)

// geometry: N=64 tokens, C=384, H=12 heads, HD=32, NW=36 masks, B=2304 windows
// ws layout (bytes):
//   [0, 196608)         bias_t  f32 [12][64][64]
//   [196608, 1081344)   qkvp    bf16 B-fragments: frag=(nb*12+ks), nb in [0,72)
//   [1081344, 1376256)  projp   bf16 B-fragments: nb in [0,24)
//   [1376256, 1387056)  table   f32 [225][12]
// O stash: bf16 fragments in the FRONT HALF of each window's d_out slab:
//   d_out + b*98304 + ((h*4+mi)*64 + lane)*16   (49152 B per window)

__global__ void k_rpe_table(const float* __restrict__ coords,
                            const float* __restrict__ w1,
                            const float* __restrict__ b1,
                            const float* __restrict__ w2,
                            float* __restrict__ table) {
  const int p = blockIdx.x;      // 0..224
  const int lane = threadIdx.x;  // 0..63
  const float c0 = coords[p * 2 + 0], c1 = coords[p * 2 + 1];
  float hm[8];
#pragma unroll
  for (int t = 0; t < 8; ++t) {
    const int j = lane * 8 + t;
    float v = fmaf(c0, w1[j * 2 + 0], fmaf(c1, w1[j * 2 + 1], b1[j]));
    hm[t] = v > 0.f ? v : 0.f;
  }
  for (int h = 0; h < 12; ++h) {
    float s = 0.f;
#pragma unroll
    for (int t = 0; t < 8; ++t) s = fmaf(hm[t], w2[h * 512 + lane * 8 + t], s);
    for (int off = 32; off >= 1; off >>= 1) s += __shfl_xor(s, off);
    if (lane == 0) table[p * 12 + h] = s;
  }
}

__global__ void k_bias_gather(const float* __restrict__ table,
                              const int* __restrict__ rel,
                              float* __restrict__ bias_t) {
  const int idx = blockIdx.x * 256 + threadIdx.x;  // 49152 total
  const int h = idx >> 12;
  const int r = idx & 4095;
  bias_t[idx] = table[rel[r] * 12 + h];
}

__global__ void k_pack_w(const float* __restrict__ qkv_w,
                         const float* __restrict__ proj_w,
                         __bf16* __restrict__ qkvp,
                         __bf16* __restrict__ projp) {
  const int gid = blockIdx.x * 256 + threadIdx.x;  // 73728 total
  const int frag = gid >> 6, lane = gid & 63;
  const int lr = lane & 15, lhi = lane >> 4;
  const float* src;
  __bf16* dst;
  if (frag < 864) {
    const int nb = frag / 12, ks = frag % 12;
    src = qkv_w + (nb * 16 + lr) * 384 + ks * 32 + lhi * 8;
    dst = qkvp + (size_t)frag * 512 + lane * 8;
  } else {
    const int f2 = frag - 864;
    const int nb = f2 / 12, ks = f2 % 12;
    src = proj_w + (nb * 16 + lr) * 384 + ks * 32 + lhi * 8;
    dst = projp + (size_t)f2 * 512 + lane * 8;
  }
#pragma unroll
  for (int j = 0; j < 8; ++j) dst[j] = (__bf16)src[j];
}

// K2: fused QKV projection + attention per window. 4 waves x 3 heads each.
// Wave-private LDS (13824 B/wave):
//   +0      q   64 rows * 72B   (stride 72 = 18 words: conflict-free-ish b128 col reads)
//   +4608   k   64 rows * 72B
//   +9216   v^T 32 rows * 136B  (dims x tokens)
//   P (softmax out) overlays q+k: 64 rows * 136B = 8704 B
//   O bounce overlays q: 64 rows * 72B
// No __syncthreads anywhere — waves free-run.
__global__ __launch_bounds__(256, 2) void k_qkv_attn(
    const float* __restrict__ x, const float* __restrict__ mask,
    const float* __restrict__ q_bias, const float* __restrict__ v_bias,
    const float* __restrict__ bias_t, const bf16x8* __restrict__ qkvp,
    char* __restrict__ ostash) {
  __shared__ __align__(16) char lds[55296];
  const int tid = threadIdx.x;
  const int b = blockIdx.x;
  const int w = tid >> 6, lane = tid & 63;
  const int lr = lane & 15, lhi = lane >> 4;
  char* wb = lds + w * 13824;
  const int mb = b % 36;
  const float scale = 0.17677669529663687f;  // 32^-0.5
  const f4 fz = {0.f, 0.f, 0.f, 0.f};
  const float* xb = x + (size_t)b * 24576;

  for (int hi = 0; hi < 3; ++hi) {
    const int h = w * 3 + hi;
    // ---- fused q,k,v projection: 64x32 each, K=384; A-frags straight from global fp32 ----
    f4 aq[4][2], ak[4][2], av[4][2];
#pragma unroll
    for (int mi = 0; mi < 4; ++mi)
#pragma unroll
      for (int nj = 0; nj < 2; ++nj) {
        aq[mi][nj] = fz;
        ak[mi][nj] = fz;
        av[mi][nj] = fz;
      }
    const bf16x8* fq = qkvp + (h * 2) * 768 + lane;
    const bf16x8* fk = qkvp + (24 + h * 2) * 768 + lane;
    const bf16x8* fv = qkvp + (48 + h * 2) * 768 + lane;
    for (int ks = 0; ks < 12; ++ks) {
      bf16x8 a[4];
#pragma unroll
      for (int mi = 0; mi < 4; ++mi) {
        const float* src = xb + (mi * 16 + lr) * 384 + ks * 32 + lhi * 8;
        const f4 u0 = *(const f4*)src;
        const f4 u1 = *(const f4*)(src + 4);
        bf16x8 t;
        t[0] = (__bf16)u0[0]; t[1] = (__bf16)u0[1];
        t[2] = (__bf16)u0[2]; t[3] = (__bf16)u0[3];
        t[4] = (__bf16)u1[0]; t[5] = (__bf16)u1[1];
        t[6] = (__bf16)u1[2]; t[7] = (__bf16)u1[3];
        a[mi] = t;
      }
      const bf16x8 bq0 = fq[ks * 64], bq1 = fq[(12 + ks) * 64];
      const bf16x8 bk0 = fk[ks * 64], bk1 = fk[(12 + ks) * 64];
      const bf16x8 bv0 = fv[ks * 64], bv1 = fv[(12 + ks) * 64];
#pragma unroll
      for (int mi = 0; mi < 4; ++mi) {
        aq[mi][0] = MFMA(a[mi], bq0, aq[mi][0]);
        aq[mi][1] = MFMA(a[mi], bq1, aq[mi][1]);
        ak[mi][0] = MFMA(a[mi], bk0, ak[mi][0]);
        ak[mi][1] = MFMA(a[mi], bk1, ak[mi][1]);
        av[mi][0] = MFMA(a[mi], bv0, av[mi][0]);
        av[mi][1] = MFMA(a[mi], bv1, av[mi][1]);
      }
    }
    // scatter q (bias+scale), k, v^T (bias) into wave-private LDS
    const float qb0 = q_bias[h * 32 + lr], qb1 = q_bias[h * 32 + 16 + lr];
    const float vb0 = v_bias[h * 32 + lr], vb1 = v_bias[h * 32 + 16 + lr];
#pragma unroll
    for (int mi = 0; mi < 4; ++mi) {
#pragma unroll
      for (int r = 0; r < 4; ++r) {
        const int row = mi * 16 + lhi * 4 + r;  // token
        *(__bf16*)(wb + row * 72 + lr * 2) = (__bf16)((aq[mi][0][r] + qb0) * scale);
        *(__bf16*)(wb + row * 72 + (16 + lr) * 2) = (__bf16)((aq[mi][1][r] + qb1) * scale);
        *(__bf16*)(wb + 4608 + row * 72 + lr * 2) = (__bf16)ak[mi][0][r];
        *(__bf16*)(wb + 4608 + row * 72 + (16 + lr) * 2) = (__bf16)ak[mi][1][r];
        *(__bf16*)(wb + 9216 + lr * 136 + row * 2) = (__bf16)(av[mi][0][r] + vb0);
        *(__bf16*)(wb + 9216 + (16 + lr) * 136 + row * 2) = (__bf16)(av[mi][1][r] + vb1);
      }
    }
    // ---- S = q k^T : 16 tiles, K=32 in one MFMA each ----
    bf16x8 fa[4], fb[4];
#pragma unroll
    for (int i = 0; i < 4; ++i) {
      const int rq = i * 16 + lr;
      fa[i] = *(const bf16x8*)(wb + rq * 72 + lhi * 16);
      fb[i] = *(const bf16x8*)(wb + 4608 + rq * 72 + lhi * 16);
    }
    f4 s[4][4];
#pragma unroll
    for (int mi = 0; mi < 4; ++mi)
#pragma unroll
      for (int nj = 0; nj < 4; ++nj) s[mi][nj] = MFMA(fa[mi], fb[nj], fz);
    // ---- bias + mask + softmax(rows), write P bf16 over q+k region ----
    const float* bp = bias_t + h * 4096;
    const float* mp = mask + mb * 4096;
#pragma unroll
    for (int mi = 0; mi < 4; ++mi) {
#pragma unroll
      for (int r = 0; r < 4; ++r) {
        const int row = mi * 16 + lhi * 4 + r;
        float v0 = s[mi][0][r] + bp[row * 64 + lr] + mp[row * 64 + lr];
        float v1 = s[mi][1][r] + bp[row * 64 + 16 + lr] + mp[row * 64 + 16 + lr];
        float v2 = s[mi][2][r] + bp[row * 64 + 32 + lr] + mp[row * 64 + 32 + lr];
        float v3 = s[mi][3][r] + bp[row * 64 + 48 + lr] + mp[row * 64 + 48 + lr];
        float mx = fmaxf(fmaxf(v0, v1), fmaxf(v2, v3));
        mx = fmaxf(mx, __shfl_xor(mx, 1));
        mx = fmaxf(mx, __shfl_xor(mx, 2));
        mx = fmaxf(mx, __shfl_xor(mx, 4));
        mx = fmaxf(mx, __shfl_xor(mx, 8));
        v0 = __expf(v0 - mx);
        v1 = __expf(v1 - mx);
        v2 = __expf(v2 - mx);
        v3 = __expf(v3 - mx);
        float sm = v0 + v1 + v2 + v3;
        sm += __shfl_xor(sm, 1);
        sm += __shfl_xor(sm, 2);
        sm += __shfl_xor(sm, 4);
        sm += __shfl_xor(sm, 8);
        const float inv = 1.0f / sm;
        *(__bf16*)(wb + row * 136 + lr * 2) = (__bf16)(v0 * inv);
        *(__bf16*)(wb + row * 136 + (16 + lr) * 2) = (__bf16)(v1 * inv);
        *(__bf16*)(wb + row * 136 + (32 + lr) * 2) = (__bf16)(v2 * inv);
        *(__bf16*)(wb + row * 136 + (48 + lr) * 2) = (__bf16)(v3 * inv);
      }
    }
    // ---- O = P V : K=64 as two MFMA k-steps ----
    f4 o[4][2];
#pragma unroll
    for (int mi = 0; mi < 4; ++mi) {
      o[mi][0] = fz;
      o[mi][1] = fz;
    }
#pragma unroll
    for (int kh = 0; kh < 2; ++kh) {
      bf16x8 pa[4], vv[2];
#pragma unroll
      for (int mi = 0; mi < 4; ++mi)
        pa[mi] = *(const bf16x8*)(wb + (mi * 16 + lr) * 136 + kh * 64 + lhi * 16);
      vv[0] = *(const bf16x8*)(wb + 9216 + lr * 136 + kh * 64 + lhi * 16);
      vv[1] = *(const bf16x8*)(wb + 9216 + (16 + lr) * 136 + kh * 64 + lhi * 16);
#pragma unroll
      for (int mi = 0; mi < 4; ++mi) {
        o[mi][0] = MFMA(pa[mi], vv[0], o[mi][0]);
        o[mi][1] = MFMA(pa[mi], vv[1], o[mi][1]);
      }
    }
    // ---- O -> bf16 fragment layout via LDS bounce (q region, now dead), coalesced store ----
#pragma unroll
    for (int mi = 0; mi < 4; ++mi) {
#pragma unroll
      for (int r = 0; r < 4; ++r) {
        const int row = mi * 16 + lhi * 4 + r;
        *(__bf16*)(wb + row * 72 + lr * 2) = (__bf16)o[mi][0][r];
        *(__bf16*)(wb + row * 72 + (16 + lr) * 2) = (__bf16)o[mi][1][r];
      }
    }
    bf16x8* op = (bf16x8*)(ostash + (size_t)b * 98304) + (h * 4) * 64 + lane;
#pragma unroll
    for (int mi = 0; mi < 4; ++mi)
      op[mi * 64] = *(const bf16x8*)(wb + (mi * 16 + lr) * 72 + lhi * 16);
  }
}

// K3: out = attn_out @ proj_w^T + proj_b. One window per block, no LDS.
// Reads the O stash from the front half of its own d_out slab, barriers, overwrites.
__global__ __launch_bounds__(256, 2) void k_proj(const float* __restrict__ proj_b,
                                                 const bf16x8* __restrict__ projp,
                                                 float* out) {
  const int tid = threadIdx.x;
  const int b = blockIdx.x;
  const int w = tid >> 6, lane = tid & 63;
  const int lr = lane & 15, lhi = lane >> 4;
  const f4 fz = {0.f, 0.f, 0.f, 0.f};
  f4 po[4][6];
#pragma unroll
  for (int mi = 0; mi < 4; ++mi)
#pragma unroll
    for (int nj = 0; nj < 6; ++nj) po[mi][nj] = fz;
  const bf16x8* astash = (const bf16x8*)((const char*)out + (size_t)b * 98304);
  const bf16x8* fw = projp + (w * 6) * 768 + lane;
  for (int ks = 0; ks < 12; ++ks) {  // ks = head
    bf16x8 a[4];
#pragma unroll
    for (int mi = 0; mi < 4; ++mi) a[mi] = astash[(ks * 4 + mi) * 64 + lane];
    bf16x8 bw[6];
#pragma unroll
    for (int nj = 0; nj < 6; ++nj) bw[nj] = fw[(nj * 12 + ks) * 64];
#pragma unroll
    for (int mi = 0; mi < 4; ++mi)
#pragma unroll
      for (int nj = 0; nj < 6; ++nj) po[mi][nj] = MFMA(a[mi], bw[nj], po[mi][nj]);
  }
  __syncthreads();  // all waves' stash loads consumed before any store overwrites the slab
  float* ob = out + (size_t)b * 24576;
#pragma unroll
  for (int nj = 0; nj < 6; ++nj) {
    const int col = w * 96 + nj * 16 + lr;
    const float pb = proj_b[col];
#pragma unroll
    for (int mi = 0; mi < 4; ++mi)
#pragma unroll
      for (int r = 0; r < 4; ++r) {
        const int row = mi * 16 + lhi * 4 + r;
        ob[row * 384 + col] = po[mi][nj][r] + pb;
      }
  }
}

extern "C" void kernel_launch(void* const* d_in, const int* in_sizes, int n_in,
                              void* d_out, int out_size, void* d_ws, size_t ws_size,
                              hipStream_t stream) {
  const float* x = (const float*)d_in[0];
  const float* mask = (const float*)d_in[1];
  const float* qkv_w = (const float*)d_in[2];
  const float* q_bias = (const float*)d_in[3];
  const float* v_bias = (const float*)d_in[4];
  const float* rpe_w1 = (const float*)d_in[5];
  const float* rpe_b1 = (const float*)d_in[6];
  const float* rpe_w2 = (const float*)d_in[7];
  const float* proj_w = (const float*)d_in[8];
  const float* proj_b = (const float*)d_in[9];
  const float* coords = (const float*)d_in[10];
  const int* rel = (const int*)d_in[11];
  float* out = (float*)d_out;

  char* ws = (char*)d_ws;
  float* bias_t = (float*)(ws);             // 196608 B
  __bf16* qkvp = (__bf16*)(ws + 196608);    // 884736 B
  __bf16* projp = (__bf16*)(ws + 1081344);  // 294912 B
  float* table = (float*)(ws + 1376256);    // 10800 B

  k_rpe_table<<<225, 64, 0, stream>>>(coords, rpe_w1, rpe_b1, rpe_w2, table);
  k_bias_gather<<<192, 256, 0, stream>>>(table, rel, bias_t);
  k_pack_w<<<288, 256, 0, stream>>>(qkv_w, proj_w, qkvp, projp);
  k_qkv_attn<<<2304, 256, 0, stream>>>(x, mask, q_bias, v_bias, bias_t,
                                       (const bf16x8*)qkvp, (char*)d_out);
  k_proj<<<2304, 256, 0, stream>>>(proj_b, (const bf16x8*)projp, out);
}

// Round 3
// 576.232 us; speedup vs baseline: 2.4069x; 2.4069x over previous
//
#include <hip/hip_runtime.h>

typedef __attribute__((ext_vector_type(8))) __bf16 bf16x8;
typedef __attribute__((ext_vector_type(4))) float f4;

#define MFMA(a, b, c) __builtin_amdgcn_mfma_f32_16x16x32_bf16((a), (b), (c), 0, 0, 0)

// geometry: N=64 tokens, C=384, H=12 heads, HD=32, NW=36 masks, B=2304 windows
// ws layout (bytes):
//   [0, 196608)         bias_t  f32 [12][64][64]
//   [196608, 1081344)   qkvp    bf16 B-fragments: frag=(nb*12+ks), nb in [0,72)
//   [1081344, 1376256)  projp   bf16 B-fragments: nb in [0,24)
//   [1376256, 1387056)  table   f32 [225][12]
// O stash: bf16 fragments in the FRONT HALF of each window's d_out slab:
//   d_out + b*98304 + ((h*4+mi)*64 + lane)*16   (49152 B per window)

__device__ inline unsigned pk2(float a, float b) {
  unsigned short ha = __builtin_bit_cast(unsigned short, (__bf16)a);
  unsigned short hb = __builtin_bit_cast(unsigned short, (__bf16)b);
  return (unsigned)ha | ((unsigned)hb << 16);
}

__global__ void k_rpe_table(const float* __restrict__ coords,
                            const float* __restrict__ w1,
                            const float* __restrict__ b1,
                            const float* __restrict__ w2,
                            float* __restrict__ table) {
  const int p = blockIdx.x;      // 0..224
  const int lane = threadIdx.x;  // 0..63
  const float c0 = coords[p * 2 + 0], c1 = coords[p * 2 + 1];
  float hm[8];
#pragma unroll
  for (int t = 0; t < 8; ++t) {
    const int j = lane * 8 + t;
    float v = fmaf(c0, w1[j * 2 + 0], fmaf(c1, w1[j * 2 + 1], b1[j]));
    hm[t] = v > 0.f ? v : 0.f;
  }
  for (int h = 0; h < 12; ++h) {
    float s = 0.f;
#pragma unroll
    for (int t = 0; t < 8; ++t) s = fmaf(hm[t], w2[h * 512 + lane * 8 + t], s);
    for (int off = 32; off >= 1; off >>= 1) s += __shfl_xor(s, off);
    if (lane == 0) table[p * 12 + h] = s;
  }
}

__global__ void k_bias_gather(const float* __restrict__ table,
                              const int* __restrict__ rel,
                              float* __restrict__ bias_t) {
  const int idx = blockIdx.x * 256 + threadIdx.x;  // 49152 total
  const int h = idx >> 12;
  const int r = idx & 4095;
  bias_t[idx] = table[rel[r] * 12 + h];
}

__global__ void k_pack_w(const float* __restrict__ qkv_w,
                         const float* __restrict__ proj_w,
                         __bf16* __restrict__ qkvp,
                         __bf16* __restrict__ projp) {
  const int gid = blockIdx.x * 256 + threadIdx.x;  // 73728 total
  const int frag = gid >> 6, lane = gid & 63;
  const int lr = lane & 15, lhi = lane >> 4;
  const float* src;
  __bf16* dst;
  if (frag < 864) {
    const int nb = frag / 12, ks = frag % 12;
    src = qkv_w + (nb * 16 + lr) * 384 + ks * 32 + lhi * 8;
    dst = qkvp + (size_t)frag * 512 + lane * 8;
  } else {
    const int f2 = frag - 864;
    const int nb = f2 / 12, ks = f2 % 12;
    src = proj_w + (nb * 16 + lr) * 384 + ks * 32 + lhi * 8;
    dst = projp + (size_t)f2 * 512 + lane * 8;
  }
#pragma unroll
  for (int j = 0; j < 8; ++j) dst[j] = (__bf16)src[j];
}

// K2: one window per block; 768 threads = 12 waves, ONE head per wave.
// LDS: [0,49152) X bf16, 64 rows * 768B, byte ^= ((row&7)<<4) swizzle (shared)
//      [49152 + w*9216): wave-private:
//         +0     q   64 rows * 72B
//         +4608  k   64 rows * 72B
//         P (softmax out) overlays q+k: 64 rows * 136B = 8704 <= 9216
//         O bounce overlays q: 64 rows * 72B
// V never touches LDS: register->register shuffle re-fragmentation.
// One __syncthreads (after X staging); everything else wave-private.
__global__ __launch_bounds__(768, 3) void k_qkv_attn(
    const float* __restrict__ x, const float* __restrict__ mask,
    const float* __restrict__ q_bias, const float* __restrict__ v_bias,
    const float* __restrict__ bias_t, const bf16x8* __restrict__ qkvp,
    char* __restrict__ ostash) {
  __shared__ __align__(16) char lds[159744];
  const int tid = threadIdx.x;
  const int b = blockIdx.x;

  // ---- stage X (64x384 fp32 -> bf16) into swizzled LDS ----
  {
    const f4* xp = (const f4*)(x + (size_t)b * 24576);
#pragma unroll
    for (int it = 0; it < 8; ++it) {
      const int idx = tid + it * 768;  // 0..6143 float4's
      const int row = idx / 96;
      const int c4 = idx % 96;
      f4 v = xp[idx];
      unsigned long long pkw =
          (unsigned long long)pk2(v[0], v[1]) |
          ((unsigned long long)pk2(v[2], v[3]) << 32);
      *(unsigned long long*)(lds + row * 768 + ((c4 * 8) ^ ((row & 7) << 4))) = pkw;
    }
  }
  __syncthreads();

  const int w = tid >> 6, lane = tid & 63;
  const int lr = lane & 15, lhi = lane >> 4;
  const int h = w;  // one head per wave
  char* wb = lds + 49152 + w * 9216;
  const int mb = b % 36;
  const float scale = 0.17677669529663687f;  // 32^-0.5
  const f4 fz = {0.f, 0.f, 0.f, 0.f};

  // ---- pass 1: q,k projection (64x32 each, K=384) ----
  {
    f4 aq[4][2], ak[4][2];
#pragma unroll
    for (int mi = 0; mi < 4; ++mi)
#pragma unroll
      for (int nj = 0; nj < 2; ++nj) {
        aq[mi][nj] = fz;
        ak[mi][nj] = fz;
      }
    const bf16x8* fq = qkvp + (h * 2) * 768 + lane;
    const bf16x8* fk = qkvp + (24 + h * 2) * 768 + lane;
    for (int ks = 0; ks < 12; ++ks) {
      bf16x8 a[4];
#pragma unroll
      for (int mi = 0; mi < 4; ++mi) {
        const int row = mi * 16 + lr;
        a[mi] = *(const bf16x8*)(lds + row * 768 +
                                 ((ks * 64 + lhi * 16) ^ ((row & 7) << 4)));
      }
      const bf16x8 bq0 = fq[ks * 64], bq1 = fq[(12 + ks) * 64];
      const bf16x8 bk0 = fk[ks * 64], bk1 = fk[(12 + ks) * 64];
#pragma unroll
      for (int mi = 0; mi < 4; ++mi) {
        aq[mi][0] = MFMA(a[mi], bq0, aq[mi][0]);
        aq[mi][1] = MFMA(a[mi], bq1, aq[mi][1]);
        ak[mi][0] = MFMA(a[mi], bk0, ak[mi][0]);
        ak[mi][1] = MFMA(a[mi], bk1, ak[mi][1]);
      }
    }
    const float qb0 = q_bias[h * 32 + lr], qb1 = q_bias[h * 32 + 16 + lr];
#pragma unroll
    for (int mi = 0; mi < 4; ++mi) {
#pragma unroll
      for (int r = 0; r < 4; ++r) {
        const int row = mi * 16 + lhi * 4 + r;  // token
        *(__bf16*)(wb + row * 72 + lr * 2) = (__bf16)((aq[mi][0][r] + qb0) * scale);
        *(__bf16*)(wb + row * 72 + (16 + lr) * 2) = (__bf16)((aq[mi][1][r] + qb1) * scale);
        *(__bf16*)(wb + 4608 + row * 72 + lr * 2) = (__bf16)ak[mi][0][r];
        *(__bf16*)(wb + 4608 + row * 72 + (16 + lr) * 2) = (__bf16)ak[mi][1][r];
      }
    }
  }

  // ---- pass 2: v projection; stays in registers (packed bf16 pairs) ----
  unsigned pkv[4][2][2];
  {
    f4 av[4][2];
#pragma unroll
    for (int mi = 0; mi < 4; ++mi) {
      av[mi][0] = fz;
      av[mi][1] = fz;
    }
    const bf16x8* fv = qkvp + (48 + h * 2) * 768 + lane;
    for (int ks = 0; ks < 12; ++ks) {
      bf16x8 a[4];
#pragma unroll
      for (int mi = 0; mi < 4; ++mi) {
        const int row = mi * 16 + lr;
        a[mi] = *(const bf16x8*)(lds + row * 768 +
                                 ((ks * 64 + lhi * 16) ^ ((row & 7) << 4)));
      }
      const bf16x8 bv0 = fv[ks * 64], bv1 = fv[(12 + ks) * 64];
#pragma unroll
      for (int mi = 0; mi < 4; ++mi) {
        av[mi][0] = MFMA(a[mi], bv0, av[mi][0]);
        av[mi][1] = MFMA(a[mi], bv1, av[mi][1]);
      }
    }
    const float vb0 = v_bias[h * 32 + lr], vb1 = v_bias[h * 32 + 16 + lr];
#pragma unroll
    for (int mi = 0; mi < 4; ++mi) {
      pkv[mi][0][0] = pk2(av[mi][0][0] + vb0, av[mi][0][1] + vb0);
      pkv[mi][0][1] = pk2(av[mi][0][2] + vb0, av[mi][0][3] + vb0);
      pkv[mi][1][0] = pk2(av[mi][1][0] + vb1, av[mi][1][1] + vb1);
      pkv[mi][1][1] = pk2(av[mi][1][2] + vb1, av[mi][1][3] + vb1);
    }
  }

  // ---- S = q k^T ----
  f4 s[4][4];
  {
    bf16x8 fa[4], fb[4];
#pragma unroll
    for (int i = 0; i < 4; ++i) {
      const int rq = i * 16 + lr;
      fa[i] = *(const bf16x8*)(wb + rq * 72 + lhi * 16);
      fb[i] = *(const bf16x8*)(wb + 4608 + rq * 72 + lhi * 16);
    }
#pragma unroll
    for (int mi = 0; mi < 4; ++mi)
#pragma unroll
      for (int nj = 0; nj < 4; ++nj) s[mi][nj] = MFMA(fa[mi], fb[nj], fz);
  }

  // ---- bias + mask + softmax(rows), write P bf16 over q+k region ----
  {
    const float* bp = bias_t + h * 4096;
    const float* mp = mask + mb * 4096;
#pragma unroll
    for (int mi = 0; mi < 4; ++mi) {
#pragma unroll
      for (int r = 0; r < 4; ++r) {
        const int row = mi * 16 + lhi * 4 + r;
        float v0 = s[mi][0][r] + bp[row * 64 + lr] + mp[row * 64 + lr];
        float v1 = s[mi][1][r] + bp[row * 64 + 16 + lr] + mp[row * 64 + 16 + lr];
        float v2 = s[mi][2][r] + bp[row * 64 + 32 + lr] + mp[row * 64 + 32 + lr];
        float v3 = s[mi][3][r] + bp[row * 64 + 48 + lr] + mp[row * 64 + 48 + lr];
        float mx = fmaxf(fmaxf(v0, v1), fmaxf(v2, v3));
        mx = fmaxf(mx, __shfl_xor(mx, 1));
        mx = fmaxf(mx, __shfl_xor(mx, 2));
        mx = fmaxf(mx, __shfl_xor(mx, 4));
        mx = fmaxf(mx, __shfl_xor(mx, 8));
        v0 = __expf(v0 - mx);
        v1 = __expf(v1 - mx);
        v2 = __expf(v2 - mx);
        v3 = __expf(v3 - mx);
        float sm = v0 + v1 + v2 + v3;
        sm += __shfl_xor(sm, 1);
        sm += __shfl_xor(sm, 2);
        sm += __shfl_xor(sm, 4);
        sm += __shfl_xor(sm, 8);
        const float inv = 1.0f / sm;
        *(__bf16*)(wb + row * 136 + lr * 2) = (__bf16)(v0 * inv);
        *(__bf16*)(wb + row * 136 + (16 + lr) * 2) = (__bf16)(v1 * inv);
        *(__bf16*)(wb + row * 136 + (32 + lr) * 2) = (__bf16)(v2 * inv);
        *(__bf16*)(wb + row * 136 + (48 + lr) * 2) = (__bf16)(v3 * inv);
      }
    }
  }

  // ---- O = P V : v B-fragments built by cross-lane shuffle of pkv ----
  f4 o[4][2];
#pragma unroll
  for (int mi = 0; mi < 4; ++mi) {
    o[mi][0] = fz;
    o[mi][1] = fz;
  }
  {
    const int srcA = lr + 32 * (lhi & 1);
    const int srcB = srcA + 16;
    const bool hiSel = lhi >= 2;
#pragma unroll
    for (int kh = 0; kh < 2; ++kh) {
      bf16x8 pa[4];
#pragma unroll
      for (int mi = 0; mi < 4; ++mi)
        pa[mi] = *(const bf16x8*)(wb + (mi * 16 + lr) * 136 + kh * 64 + lhi * 16);
      bf16x8 vv[2];
#pragma unroll
      for (int nj = 0; nj < 2; ++nj) {
        const unsigned a0 = (unsigned)__shfl((int)pkv[2 * kh][nj][0], srcA);
        const unsigned b0 = (unsigned)__shfl((int)pkv[2 * kh + 1][nj][0], srcA);
        const unsigned a1 = (unsigned)__shfl((int)pkv[2 * kh][nj][1], srcA);
        const unsigned b1 = (unsigned)__shfl((int)pkv[2 * kh + 1][nj][1], srcA);
        const unsigned a2 = (unsigned)__shfl((int)pkv[2 * kh][nj][0], srcB);
        const unsigned b2 = (unsigned)__shfl((int)pkv[2 * kh + 1][nj][0], srcB);
        const unsigned a3 = (unsigned)__shfl((int)pkv[2 * kh][nj][1], srcB);
        const unsigned b3 = (unsigned)__shfl((int)pkv[2 * kh + 1][nj][1], srcB);
        union {
          unsigned u[4];
          bf16x8 v8;
        } cv;
        cv.u[0] = hiSel ? b0 : a0;
        cv.u[1] = hiSel ? b1 : a1;
        cv.u[2] = hiSel ? b2 : a2;
        cv.u[3] = hiSel ? b3 : a3;
        vv[nj] = cv.v8;
      }
#pragma unroll
      for (int mi = 0; mi < 4; ++mi) {
        o[mi][0] = MFMA(pa[mi], vv[0], o[mi][0]);
        o[mi][1] = MFMA(pa[mi], vv[1], o[mi][1]);
      }
    }
  }

  // ---- O -> bf16 fragment layout via LDS bounce (q region, now dead) ----
#pragma unroll
  for (int mi = 0; mi < 4; ++mi) {
#pragma unroll
    for (int r = 0; r < 4; ++r) {
      const int row = mi * 16 + lhi * 4 + r;
      *(__bf16*)(wb + row * 72 + lr * 2) = (__bf16)o[mi][0][r];
      *(__bf16*)(wb + row * 72 + (16 + lr) * 2) = (__bf16)o[mi][1][r];
    }
  }
  bf16x8* op = (bf16x8*)(ostash + (size_t)b * 98304) + (h * 4) * 64 + lane;
#pragma unroll
  for (int mi = 0; mi < 4; ++mi)
    op[mi * 64] = *(const bf16x8*)(wb + (mi * 16 + lr) * 72 + lhi * 16);
}

// K3: out = attn_out @ proj_w^T + proj_b. One window per block, no LDS.
// Reads the O stash from the front half of its own d_out slab, barriers, overwrites.
__global__ __launch_bounds__(256, 3) void k_proj(const float* __restrict__ proj_b,
                                                 const bf16x8* __restrict__ projp,
                                                 float* out) {
  const int tid = threadIdx.x;
  const int b = blockIdx.x;
  const int w = tid >> 6, lane = tid & 63;
  const int lr = lane & 15, lhi = lane >> 4;
  const f4 fz = {0.f, 0.f, 0.f, 0.f};
  f4 po[4][6];
#pragma unroll
  for (int mi = 0; mi < 4; ++mi)
#pragma unroll
    for (int nj = 0; nj < 6; ++nj) po[mi][nj] = fz;
  const bf16x8* astash = (const bf16x8*)((const char*)out + (size_t)b * 98304);
  const bf16x8* fw = projp + (w * 6) * 768 + lane;
  for (int ks = 0; ks < 12; ++ks) {  // ks = head
    bf16x8 a[4];
#pragma unroll
    for (int mi = 0; mi < 4; ++mi) a[mi] = astash[(ks * 4 + mi) * 64 + lane];
    bf16x8 bw[6];
#pragma unroll
    for (int nj = 0; nj < 6; ++nj) bw[nj] = fw[(nj * 12 + ks) * 64];
#pragma unroll
    for (int mi = 0; mi < 4; ++mi)
#pragma unroll
      for (int nj = 0; nj < 6; ++nj) po[mi][nj] = MFMA(a[mi], bw[nj], po[mi][nj]);
  }
  __syncthreads();  // all waves' stash loads consumed before any store overwrites the slab
  float* ob = out + (size_t)b * 24576;
#pragma unroll
  for (int nj = 0; nj < 6; ++nj) {
    const int col = w * 96 + nj * 16 + lr;
    const float pb = proj_b[col];
#pragma unroll
    for (int mi = 0; mi < 4; ++mi)
#pragma unroll
      for (int r = 0; r < 4; ++r) {
        const int row = mi * 16 + lhi * 4 + r;
        ob[row * 384 + col] = po[mi][nj][r] + pb;
      }
  }
}

extern "C" void kernel_launch(void* const* d_in, const int* in_sizes, int n_in,
                              void* d_out, int out_size, void* d_ws, size_t ws_size,
                              hipStream_t stream) {
  const float* x = (const float*)d_in[0];
  const float* mask = (const float*)d_in[1];
  const float* qkv_w = (const float*)d_in[2];
  const float* q_bias = (const float*)d_in[3];
  const float* v_bias = (const float*)d_in[4];
  const float* rpe_w1 = (const float*)d_in[5];
  const float* rpe_b1 = (const float*)d_in[6];
  const float* rpe_w2 = (const float*)d_in[7];
  const float* proj_w = (const float*)d_in[8];
  const float* proj_b = (const float*)d_in[9];
  const float* coords = (const float*)d_in[10];
  const int* rel = (const int*)d_in[11];
  float* out = (float*)d_out;

  char* ws = (char*)d_ws;
  float* bias_t = (float*)(ws);             // 196608 B
  __bf16* qkvp = (__bf16*)(ws + 196608);    // 884736 B
  __bf16* projp = (__bf16*)(ws + 1081344);  // 294912 B
  float* table = (float*)(ws + 1376256);    // 10800 B

  k_rpe_table<<<225, 64, 0, stream>>>(coords, rpe_w1, rpe_b1, rpe_w2, table);
  k_bias_gather<<<192, 256, 0, stream>>>(table, rel, bias_t);
  k_pack_w<<<288, 256, 0, stream>>>(qkv_w, proj_w, qkvp, projp);
  k_qkv_attn<<<2304, 768, 0, stream>>>(x, mask, q_bias, v_bias, bias_t,
                                       (const bf16x8*)qkvp, (char*)d_out);
  k_proj<<<2304, 256, 0, stream>>>(proj_b, (const bf16x8*)projp, out);
}

// Round 4
// 391.439 us; speedup vs baseline: 3.5432x; 1.4721x over previous
//
#include <hip/hip_runtime.h>

typedef __attribute__((ext_vector_type(8))) __bf16 bf16x8;
typedef __attribute__((ext_vector_type(4))) float f4;
typedef __attribute__((ext_vector_type(2))) unsigned int u32x2;

#define MFMA(a, b, c) __builtin_amdgcn_mfma_f32_16x16x32_bf16((a), (b), (c), 0, 0, 0)

// geometry: N=64 tokens, C=384, H=12 heads, HD=32, NW=36 masks, B=2304 windows
// ws layout (bytes):
//   [0, 196608)         bias_t  f32 [12][64][64]
//   [196608, 1081344)   qkvp    bf16 B-fragments: frag=(nb*12+ks), nb in [0,72)
//   [1081344, 1376256)  projp   bf16 B-fragments: nb in [0,24)
//   [1376256, 1387056)  table   f32 [225][12]

__device__ inline unsigned pk2(float a, float b) {
  unsigned short ha = __builtin_bit_cast(unsigned short, (__bf16)a);
  unsigned short hb = __builtin_bit_cast(unsigned short, (__bf16)b);
  return (unsigned)ha | ((unsigned)hb << 16);
}

__global__ void k_rpe_table(const float* __restrict__ coords,
                            const float* __restrict__ w1,
                            const float* __restrict__ b1,
                            const float* __restrict__ w2,
                            float* __restrict__ table) {
  const int p = blockIdx.x;      // 0..224
  const int lane = threadIdx.x;  // 0..63
  const float c0 = coords[p * 2 + 0], c1 = coords[p * 2 + 1];
  float hm[8];
#pragma unroll
  for (int t = 0; t < 8; ++t) {
    const int j = lane * 8 + t;
    float v = fmaf(c0, w1[j * 2 + 0], fmaf(c1, w1[j * 2 + 1], b1[j]));
    hm[t] = v > 0.f ? v : 0.f;
  }
  for (int h = 0; h < 12; ++h) {
    float s = 0.f;
#pragma unroll
    for (int t = 0; t < 8; ++t) s = fmaf(hm[t], w2[h * 512 + lane * 8 + t], s);
    for (int off = 32; off >= 1; off >>= 1) s += __shfl_xor(s, off);
    if (lane == 0) table[p * 12 + h] = s;
  }
}

__global__ void k_bias_gather(const float* __restrict__ table,
                              const int* __restrict__ rel,
                              float* __restrict__ bias_t) {
  const int idx = blockIdx.x * 256 + threadIdx.x;  // 49152 total
  const int h = idx >> 12;
  const int r = idx & 4095;
  bias_t[idx] = table[rel[r] * 12 + h];
}

__global__ void k_pack_w(const float* __restrict__ qkv_w,
                         const float* __restrict__ proj_w,
                         __bf16* __restrict__ qkvp,
                         __bf16* __restrict__ projp) {
  const int gid = blockIdx.x * 256 + threadIdx.x;  // 73728 total
  const int frag = gid >> 6, lane = gid & 63;
  const int lr = lane & 15, lhi = lane >> 4;
  const float* src;
  __bf16* dst;
  if (frag < 864) {
    const int nb = frag / 12, ks = frag % 12;
    src = qkv_w + (nb * 16 + lr) * 384 + ks * 32 + lhi * 8;
    dst = qkvp + (size_t)frag * 512 + lane * 8;
  } else {
    const int f2 = frag - 864;
    const int nb = f2 / 12, ks = f2 % 12;
    src = proj_w + (nb * 16 + lr) * 384 + ks * 32 + lhi * 8;
    dst = projp + (size_t)f2 * 512 + lane * 8;
  }
#pragma unroll
  for (int j = 0; j < 8; ++j) dst[j] = (__bf16)src[j];
}

// Fused kernel: one window per block; 768 threads = 12 waves, ONE head per wave.
// LDS: [0,49152)  X bf16 64 rows * 768B, byte ^= ((row&7)<<4)  -> later reused as attn_out
//      [49152 + w*9216): wave-private q (64*72B) / k (+4608, 64*72B); P overlays (64*136B)
// Phases: stage X | qk proj | v proj (regs) | S^T=mfma(K,Q) | no-max softmax (2 shuffles/row)
//         | PV (V via lane shuffle) | barrier | O->attn_out (X region) | barrier | proj GEMM
__global__ __launch_bounds__(768, 3) void k_fused(
    const float* __restrict__ x, const float* __restrict__ mask,
    const float* __restrict__ q_bias, const float* __restrict__ v_bias,
    const float* __restrict__ bias_t, const bf16x8* __restrict__ qkvp,
    const bf16x8* __restrict__ projp, const float* __restrict__ proj_b,
    float* __restrict__ out) {
  __shared__ __align__(16) char lds[159744];
  const int tid = threadIdx.x;
  const int b = blockIdx.x;

  // ---- stage X (64x384 fp32 -> bf16) into swizzled LDS ----
  {
    const f4* xp = (const f4*)(x + (size_t)b * 24576);
#pragma unroll
    for (int it = 0; it < 8; ++it) {
      const int idx = tid + it * 768;  // 0..6143 float4's
      const int row = idx / 96;
      const int c4 = idx % 96;
      f4 v = xp[idx];
      unsigned long long pkw =
          (unsigned long long)pk2(v[0], v[1]) |
          ((unsigned long long)pk2(v[2], v[3]) << 32);
      *(unsigned long long*)(lds + row * 768 + ((c4 * 8) ^ ((row & 7) << 4))) = pkw;
    }
  }
  __syncthreads();

  const int w = tid >> 6, lane = tid & 63;
  const int lr = lane & 15, lhi = lane >> 4;
  const int h = w;  // one head per wave
  char* wb = lds + 49152 + w * 9216;
  const int mb = b % 36;
  const float scale = 0.17677669529663687f;  // 32^-0.5
  const f4 fz = {0.f, 0.f, 0.f, 0.f};

  // ---- pass 1: q,k projection (64x32 each, K=384), explicit B-frag prefetch ----
  {
    f4 aq[4][2], ak[4][2];
#pragma unroll
    for (int mi = 0; mi < 4; ++mi)
#pragma unroll
      for (int nj = 0; nj < 2; ++nj) {
        aq[mi][nj] = fz;
        ak[mi][nj] = fz;
      }
    const bf16x8* fq = qkvp + h * 1536 + lane;
    const bf16x8* fk = qkvp + 18432 + h * 1536 + lane;
    bf16x8 cq0 = fq[0], cq1 = fq[768], ck0 = fk[0], ck1 = fk[768];
#pragma unroll
    for (int ks = 0; ks < 12; ++ks) {
      bf16x8 a[4];
#pragma unroll
      for (int mi = 0; mi < 4; ++mi) {
        const int row = mi * 16 + lr;
        a[mi] = *(const bf16x8*)(lds + row * 768 +
                                 ((ks * 64 + lhi * 16) ^ ((row & 7) << 4)));
      }
      bf16x8 nq0, nq1, nk0, nk1;
      if (ks < 11) {
        nq0 = fq[(ks + 1) * 64];
        nq1 = fq[(ks + 13) * 64];
        nk0 = fk[(ks + 1) * 64];
        nk1 = fk[(ks + 13) * 64];
      }
#pragma unroll
      for (int mi = 0; mi < 4; ++mi) {
        aq[mi][0] = MFMA(a[mi], cq0, aq[mi][0]);
        aq[mi][1] = MFMA(a[mi], cq1, aq[mi][1]);
        ak[mi][0] = MFMA(a[mi], ck0, ak[mi][0]);
        ak[mi][1] = MFMA(a[mi], ck1, ak[mi][1]);
      }
      cq0 = nq0; cq1 = nq1; ck0 = nk0; ck1 = nk1;
    }
    const float qb0 = q_bias[h * 32 + lr], qb1 = q_bias[h * 32 + 16 + lr];
#pragma unroll
    for (int mi = 0; mi < 4; ++mi) {
#pragma unroll
      for (int r = 0; r < 4; ++r) {
        const int row = mi * 16 + lhi * 4 + r;  // token
        *(__bf16*)(wb + row * 72 + lr * 2) = (__bf16)((aq[mi][0][r] + qb0) * scale);
        *(__bf16*)(wb + row * 72 + (16 + lr) * 2) = (__bf16)((aq[mi][1][r] + qb1) * scale);
        *(__bf16*)(wb + 4608 + row * 72 + lr * 2) = (__bf16)ak[mi][0][r];
        *(__bf16*)(wb + 4608 + row * 72 + (16 + lr) * 2) = (__bf16)ak[mi][1][r];
      }
    }
  }

  // ---- pass 2: v projection; stays in registers (packed bf16 pairs) ----
  unsigned pkv[4][2][2];
  {
    f4 av[4][2];
#pragma unroll
    for (int mi = 0; mi < 4; ++mi) {
      av[mi][0] = fz;
      av[mi][1] = fz;
    }
    const bf16x8* fv = qkvp + 36864 + h * 1536 + lane;
    bf16x8 cv0 = fv[0], cv1 = fv[768];
#pragma unroll
    for (int ks = 0; ks < 12; ++ks) {
      bf16x8 a[4];
#pragma unroll
      for (int mi = 0; mi < 4; ++mi) {
        const int row = mi * 16 + lr;
        a[mi] = *(const bf16x8*)(lds + row * 768 +
                                 ((ks * 64 + lhi * 16) ^ ((row & 7) << 4)));
      }
      bf16x8 nv0, nv1;
      if (ks < 11) {
        nv0 = fv[(ks + 1) * 64];
        nv1 = fv[(ks + 13) * 64];
      }
#pragma unroll
      for (int mi = 0; mi < 4; ++mi) {
        av[mi][0] = MFMA(a[mi], cv0, av[mi][0]);
        av[mi][1] = MFMA(a[mi], cv1, av[mi][1]);
      }
      cv0 = nv0; cv1 = nv1;
    }
    const float vb0 = v_bias[h * 32 + lr], vb1 = v_bias[h * 32 + 16 + lr];
#pragma unroll
    for (int mi = 0; mi < 4; ++mi) {
      pkv[mi][0][0] = pk2(av[mi][0][0] + vb0, av[mi][0][1] + vb0);
      pkv[mi][0][1] = pk2(av[mi][0][2] + vb0, av[mi][0][3] + vb0);
      pkv[mi][1][0] = pk2(av[mi][1][0] + vb1, av[mi][1][1] + vb1);
      pkv[mi][1][1] = pk2(av[mi][1][2] + vb1, av[mi][1][3] + vb1);
    }
  }

  // ---- S^T = mfma(K, Q): st[mi][nj] holds S[q = nj*16+lr][k = mi*16+lhi*4+r] ----
  f4 st[4][4];
  {
    bf16x8 fqv[4], fkv[4];
#pragma unroll
    for (int i = 0; i < 4; ++i) {
      const int rt = i * 16 + lr;
      fqv[i] = *(const bf16x8*)(wb + rt * 72 + lhi * 16);          // Q frag
      fkv[i] = *(const bf16x8*)(wb + 4608 + rt * 72 + lhi * 16);   // K frag
    }
#pragma unroll
    for (int mi = 0; mi < 4; ++mi)
#pragma unroll
      for (int nj = 0; nj < 4; ++nj) st[mi][nj] = MFMA(fkv[mi], fqv[nj], fz);
  }

  // ---- no-max softmax over k (local 16-sum + 2 shuffles per q-row), P -> LDS [q][k] ----
  {
    const float* bp = bias_t + h * 4096;
    const float* mp = mask + mb * 4096;
#pragma unroll
    for (int nj = 0; nj < 4; ++nj) {
      const int q = nj * 16 + lr;
      float lsum = 0.f;
#pragma unroll
      for (int mi = 0; mi < 4; ++mi) {
        const int kbase = mi * 16 + lhi * 4;
        const f4 bb = *(const f4*)(bp + q * 64 + kbase);
        const f4 mm = *(const f4*)(mp + q * 64 + kbase);
        f4 e;
#pragma unroll
        for (int r = 0; r < 4; ++r) e[r] = __expf(st[mi][nj][r] + bb[r] + mm[r]);
        st[mi][nj] = e;
        lsum += (e[0] + e[1]) + (e[2] + e[3]);
      }
      lsum += __shfl_xor(lsum, 16);
      lsum += __shfl_xor(lsum, 32);
      const float inv = 1.0f / lsum;
#pragma unroll
      for (int mi = 0; mi < 4; ++mi) {
        u32x2 pw;
        pw[0] = pk2(st[mi][nj][0] * inv, st[mi][nj][1] * inv);
        pw[1] = pk2(st[mi][nj][2] * inv, st[mi][nj][3] * inv);
        *(u32x2*)(wb + q * 136 + (mi * 16 + lhi * 4) * 2) = pw;
      }
    }
  }

  // ---- O = P V : v B-fragments built by cross-lane shuffle of pkv ----
  f4 o[4][2];
#pragma unroll
  for (int mi = 0; mi < 4; ++mi) {
    o[mi][0] = fz;
    o[mi][1] = fz;
  }
  {
    const int srcA = lr + 32 * (lhi & 1);
    const int srcB = srcA + 16;
    const bool hiSel = lhi >= 2;
#pragma unroll
    for (int kh = 0; kh < 2; ++kh) {
      bf16x8 pa[4];
#pragma unroll
      for (int mi = 0; mi < 4; ++mi)
        pa[mi] = *(const bf16x8*)(wb + (mi * 16 + lr) * 136 + kh * 64 + lhi * 16);
      bf16x8 vv[2];
#pragma unroll
      for (int nj = 0; nj < 2; ++nj) {
        const unsigned a0 = (unsigned)__shfl((int)pkv[2 * kh][nj][0], srcA);
        const unsigned b0 = (unsigned)__shfl((int)pkv[2 * kh + 1][nj][0], srcA);
        const unsigned a1 = (unsigned)__shfl((int)pkv[2 * kh][nj][1], srcA);
        const unsigned b1 = (unsigned)__shfl((int)pkv[2 * kh + 1][nj][1], srcA);
        const unsigned a2 = (unsigned)__shfl((int)pkv[2 * kh][nj][0], srcB);
        const unsigned b2 = (unsigned)__shfl((int)pkv[2 * kh + 1][nj][0], srcB);
        const unsigned a3 = (unsigned)__shfl((int)pkv[2 * kh][nj][1], srcB);
        const unsigned b3 = (unsigned)__shfl((int)pkv[2 * kh + 1][nj][1], srcB);
        union {
          unsigned u[4];
          bf16x8 v8;
        } cv;
        cv.u[0] = hiSel ? b0 : a0;
        cv.u[1] = hiSel ? b1 : a1;
        cv.u[2] = hiSel ? b2 : a2;
        cv.u[3] = hiSel ? b3 : a3;
        vv[nj] = cv.v8;
      }
#pragma unroll
      for (int mi = 0; mi < 4; ++mi) {
        o[mi][0] = MFMA(pa[mi], vv[0], o[mi][0]);
        o[mi][1] = MFMA(pa[mi], vv[1], o[mi][1]);
      }
    }
  }

  // ---- all X reads done; reuse X region as attn_out (same swizzled layout) ----
  __syncthreads();
#pragma unroll
  for (int mi = 0; mi < 4; ++mi) {
#pragma unroll
    for (int r = 0; r < 4; ++r) {
      const int row = mi * 16 + lhi * 4 + r;
      const int sw = (row & 7) << 4;
      *(__bf16*)(lds + row * 768 + (((h * 32 + lr) * 2) ^ sw)) = (__bf16)o[mi][0][r];
      *(__bf16*)(lds + row * 768 + (((h * 32 + 16 + lr) * 2) ^ sw)) = (__bf16)o[mi][1][r];
    }
  }
  __syncthreads();

  // ---- proj: wave w computes cols [w*32, w*32+32); K=384 over attn_out ----
  {
    f4 po[4][2];
#pragma unroll
    for (int mi = 0; mi < 4; ++mi) {
      po[mi][0] = fz;
      po[mi][1] = fz;
    }
    const bf16x8* fw = projp + w * 1536 + lane;
    bf16x8 cw0 = fw[0], cw1 = fw[768];
#pragma unroll
    for (int ks = 0; ks < 12; ++ks) {
      bf16x8 a[4];
#pragma unroll
      for (int mi = 0; mi < 4; ++mi) {
        const int row = mi * 16 + lr;
        a[mi] = *(const bf16x8*)(lds + row * 768 +
                                 ((ks * 64 + lhi * 16) ^ ((row & 7) << 4)));
      }
      bf16x8 nw0, nw1;
      if (ks < 11) {
        nw0 = fw[(ks + 1) * 64];
        nw1 = fw[(ks + 13) * 64];
      }
#pragma unroll
      for (int mi = 0; mi < 4; ++mi) {
        po[mi][0] = MFMA(a[mi], cw0, po[mi][0]);
        po[mi][1] = MFMA(a[mi], cw1, po[mi][1]);
      }
      cw0 = nw0; cw1 = nw1;
    }
    float* ob = out + (size_t)b * 24576;
    const float pb0 = proj_b[w * 32 + lr];
    const float pb1 = proj_b[w * 32 + 16 + lr];
#pragma unroll
    for (int mi = 0; mi < 4; ++mi) {
#pragma unroll
      for (int r = 0; r < 4; ++r) {
        const int row = mi * 16 + lhi * 4 + r;
        ob[row * 384 + w * 32 + lr] = po[mi][0][r] + pb0;
        ob[row * 384 + w * 32 + 16 + lr] = po[mi][1][r] + pb1;
      }
    }
  }
}

extern "C" void kernel_launch(void* const* d_in, const int* in_sizes, int n_in,
                              void* d_out, int out_size, void* d_ws, size_t ws_size,
                              hipStream_t stream) {
  const float* x = (const float*)d_in[0];
  const float* mask = (const float*)d_in[1];
  const float* qkv_w = (const float*)d_in[2];
  const float* q_bias = (const float*)d_in[3];
  const float* v_bias = (const float*)d_in[4];
  const float* rpe_w1 = (const float*)d_in[5];
  const float* rpe_b1 = (const float*)d_in[6];
  const float* rpe_w2 = (const float*)d_in[7];
  const float* proj_w = (const float*)d_in[8];
  const float* proj_b = (const float*)d_in[9];
  const float* coords = (const float*)d_in[10];
  const int* rel = (const int*)d_in[11];
  float* out = (float*)d_out;

  char* ws = (char*)d_ws;
  float* bias_t = (float*)(ws);             // 196608 B
  __bf16* qkvp = (__bf16*)(ws + 196608);    // 884736 B
  __bf16* projp = (__bf16*)(ws + 1081344);  // 294912 B
  float* table = (float*)(ws + 1376256);    // 10800 B

  k_rpe_table<<<225, 64, 0, stream>>>(coords, rpe_w1, rpe_b1, rpe_w2, table);
  k_bias_gather<<<192, 256, 0, stream>>>(table, rel, bias_t);
  k_pack_w<<<288, 256, 0, stream>>>(qkv_w, proj_w, qkvp, projp);
  k_fused<<<2304, 768, 0, stream>>>(x, mask, q_bias, v_bias, bias_t,
                                    (const bf16x8*)qkvp, (const bf16x8*)projp,
                                    proj_b, out);
}